// Round 1
// baseline (3334.603 us; speedup 1.0000x reference)
//
#include <hip/hip_runtime.h>
#include <math.h>

#define NB 64
#define NS 128
#define NE 512
#define NH 512
#define NPOI_ 8192
#define NCAT_ 400
#define NF_ 128
#define H3 1536
#define NEGV -1000000000.0

__device__ inline float sigmf(float x){ return 1.0f/(1.0f + expf(-x)); }

// ---------- phase 1: attention precompute ----------
// c1[f] = sum_k W_attn[f,k]*a1[k];  c2 with a2   (f64 for argmax stability)
__global__ void k_prep_c(const float* __restrict__ W_attn, const float* __restrict__ a_attn,
                         double* __restrict__ c1d, double* __restrict__ c2d){
    int f = blockIdx.x*blockDim.x + threadIdx.x;
    if (f < NF_){
        double s1=0.0, s2=0.0;
        for (int k=0;k<NF_;k++){
            double w = (double)W_attn[f*NF_+k];
            s1 += w*(double)a_attn[k];
            s2 += w*(double)a_attn[NF_+k];
        }
        c1d[f]=s1; c2d[f]=s2;
    }
}

__global__ void k_wh(const float* __restrict__ X, const double* __restrict__ c1d,
                     const double* __restrict__ c2d, double* __restrict__ wh1, double* __restrict__ wh2){
    int p = blockIdx.x*blockDim.x + threadIdx.x;
    if (p < NPOI_){
        const float* x = X + (size_t)p*NF_;
        double s1=0.0,s2=0.0;
        for (int k=0;k<NF_;k++){ double xv=(double)x[k]; s1+=xv*c1d[k]; s2+=xv*c2d[k]; }
        wh1[p]=s1; wh2[p]=s2;
    }
}

// gh0[c] = h0 . W_hh[c,:] + b_hh[c]
__global__ void k_gh0(const float* __restrict__ h0, const float* __restrict__ W_hh,
                      const float* __restrict__ b_hh, float* __restrict__ gh0){
    int c = blockIdx.x*blockDim.x + threadIdx.x;
    if (c < H3){
        const float* w = W_hh + (size_t)c*NH;
        float s=0.f;
        for (int k=0;k<NH;k++) s += h0[k]*w[k];
        gh0[c] = s + b_hh[c];
    }
}

__device__ inline double shfl_down_d(double x, int off){
    long long v = __double_as_longlong(x);
    int lo = (int)(v & 0xffffffffLL), hi = (int)(((unsigned long long)v)>>32);
    lo = __shfl_down(lo, off); hi = __shfl_down(hi, off);
    return __longlong_as_double(((long long)hi<<32) | (unsigned long long)(unsigned int)lo);
}

// one wave per (b,j): v0/argmax over k<j (first-index ties), v1, softmax -> alpha
__global__ void k_attn(const int* __restrict__ seq, const int* __restrict__ lens,
                       const float* __restrict__ A, const double* __restrict__ wh1,
                       const double* __restrict__ wh2, float* __restrict__ alpha,
                       int* __restrict__ idxout){
    int gw = (int)((blockIdx.x*(size_t)blockDim.x + threadIdx.x) >> 6);
    int lane = threadIdx.x & 63;
    if (gw >= NB*NS) return;
    int b = gw >> 7, j = gw & 127;
    int len = lens[b];
    int q = seq[b*NS + j];
    double wq = wh2[q];
    bool jvalid = (j < len);
    double mval = -1.0e300; int mk = 0;
    for (int k0=0;k0<NS;k0+=64){
        int k = k0 + lane;
        double val = NEGV;
        if (k < j && jvalid){
            int p = seq[b*NS + k];
            double e = wh1[p] + wq;
            e = (e > 0.0) ? e : 0.2*e;
            val = e * ((double)A[(size_t)p*NPOI_ + q] + 1.0);
        }
        if (val > mval){ mval = val; mk = k; }
    }
    for (int off=32; off; off>>=1){
        double ov = shfl_down_d(mval, off);
        int ok = __shfl_down(mk, off);
        if (ov > mval || (ov == mval && ok < mk)){ mval = ov; mk = ok; }
    }
    if (lane == 0){
        double v0 = mval;
        double v1;
        if (j == 0) v1 = 0.0;
        else if (!jvalid) v1 = NEGV;
        else {
            int p = seq[b*NS + j - 1];
            double e = wh1[p] + wq;
            e = (e > 0.0) ? e : 0.2*e;
            v1 = e * ((double)A[(size_t)p*NPOI_ + q] + 1.0);
        }
        double m = fmax(v0, v1);
        double e0 = exp(v0 - m), e1 = exp(v1 - m);
        double den = e0 + e1;
        alpha[(size_t)(b*NS+j)*2 + 0] = (float)(e0/den);
        alpha[(size_t)(b*NS+j)*2 + 1] = (float)(e1/den);
        idxout[b*NS + j] = mk;
    }
}

// ---------- f32 NT GEMM: C[r,c] = sum_k A[r,k]*B[c,k] + bias[c] ----------
#define BM 128
#define BN 128
#define BKG 16
__global__ __launch_bounds__(256) void k_gemm_nt(const float* __restrict__ A, const float* __restrict__ B,
                                                 const float* __restrict__ bias, float* __restrict__ C,
                                                 int M, int N, int K, int ldc){
    __shared__ float As[BKG][BM+4];
    __shared__ float Bs[BKG][BN+4];
    int bm = blockIdx.y, bn = blockIdx.x;
    int row0 = bm*BM, col0 = bn*BN;
    int tid = threadIdx.x;
    int tx = tid & 15, ty = tid >> 4;
    float acc[8][8];
    #pragma unroll
    for (int i=0;i<8;i++)
        #pragma unroll
        for (int j=0;j<8;j++) acc[i][j]=0.f;
    for (int k0=0;k0<K;k0+=BKG){
        for (int f = tid; f < (BM*BKG/4); f += 256){
            int r = f >> 2, kq = (f & 3)*4;
            const float4 av = *(const float4*)(A + (size_t)(row0 + r)*K + k0 + kq);
            As[kq+0][r]=av.x; As[kq+1][r]=av.y; As[kq+2][r]=av.z; As[kq+3][r]=av.w;
        }
        for (int f = tid; f < (BN*BKG/4); f += 256){
            int c = f >> 2, kq = (f & 3)*4;
            int gc = col0 + c;
            float4 bv;
            if (gc < N) bv = *(const float4*)(B + (size_t)gc*K + k0 + kq);
            else bv = make_float4(0.f,0.f,0.f,0.f);
            Bs[kq+0][c]=bv.x; Bs[kq+1][c]=bv.y; Bs[kq+2][c]=bv.z; Bs[kq+3][c]=bv.w;
        }
        __syncthreads();
        #pragma unroll
        for (int k=0;k<BKG;k++){
            float a0[8], b0[8];
            *(float4*)&a0[0] = *(const float4*)&As[k][ty*8];
            *(float4*)&a0[4] = *(const float4*)&As[k][ty*8+4];
            *(float4*)&b0[0] = *(const float4*)&Bs[k][tx*8];
            *(float4*)&b0[4] = *(const float4*)&Bs[k][tx*8+4];
            #pragma unroll
            for (int i=0;i<8;i++)
                #pragma unroll
                for (int j=0;j<8;j++) acc[i][j] = fmaf(a0[i], b0[j], acc[i][j]);
        }
        __syncthreads();
    }
    for (int i=0;i<8;i++){
        int r = row0 + ty*8 + i;
        #pragma unroll
        for (int j=0;j<8;j++){
            int c = col0 + tx*8 + j;
            if (c < N) C[(size_t)r*ldc + c] = acc[i][j] + bias[c];
        }
    }
}

// ---------- scan ----------
__global__ void k_step0(const float* __restrict__ gi, const float* __restrict__ gh0,
                        const float* __restrict__ h0, float* __restrict__ xbuf){
    int t = blockIdx.x*blockDim.x + threadIdx.x;
    if (t >= NB*NH) return;
    int b = t >> 9, h = t & 511;
    const float* g = gi + (size_t)b*NS*H3;  // row (b, s=0)
    float r = sigmf(g[h] + gh0[h]);
    float z = sigmf(g[512+h] + gh0[512+h]);
    float n = tanhf(g[1024+h] + r*gh0[1024+h]);
    xbuf[(size_t)b*NS*NH + h] = (1.f-z)*n + z*h0[h];
}

// per-step fused kernel: grid (64 hb, 4 rb); WG: 16 b x 8 h; M-rows = 16b x {hid, hid2}
__global__ __launch_bounds__(256) void k_step(const float* __restrict__ gi, const float* __restrict__ W_hh,
                                              const float* __restrict__ b_hh, const float* __restrict__ alpha,
                                              const int* __restrict__ idx, float* __restrict__ xbuf, int i){
    __shared__ float Ms[32][132];
    __shared__ float Ws[24][132];
    __shared__ float Gs[32][24];
    __shared__ int rowidx[16];
    int hb = blockIdx.x, rb = blockIdx.y;
    int b0 = rb*16;
    int tid = threadIdx.x;
    if (tid < 16) rowidx[tid] = idx[(b0+tid)*NS + i];
    __syncthreads();
    float acc0=0.f, acc1=0.f, acc2=0.f;
    int r = tid & 31;     // M-row
    int wg = tid >> 5;    // 0..7 -> wcols wg*3..wg*3+2
    for (int k0=0;k0<NH;k0+=128){
        for (int f = tid; f < 1024; f += 256){   // 32 rows x 32 float4
            int rr = f >> 5; int kq = (f & 31)*4;
            int b = b0 + (rr & 15);
            int srow = (rr < 16) ? (i-1) : rowidx[rr-16];
            const float4 v = *(const float4*)(xbuf + ((size_t)b*NS + srow)*NH + k0 + kq);
            *(float4*)&Ms[rr][kq] = v;
        }
        for (int f = tid; f < 768; f += 256){    // 24 rows x 32 float4
            int wr = f >> 5; int kq = (f & 31)*4;
            int gate = wr >> 3, j = wr & 7;
            int wrow = gate*512 + hb*8 + j;
            const float4 v = *(const float4*)(W_hh + (size_t)wrow*NH + k0 + kq);
            *(float4*)&Ws[wr][kq] = v;
        }
        __syncthreads();
        #pragma unroll 8
        for (int k=0;k<128;k+=4){
            float4 a  = *(const float4*)&Ms[r][k];
            float4 w0 = *(const float4*)&Ws[wg*3+0][k];
            float4 w1 = *(const float4*)&Ws[wg*3+1][k];
            float4 w2 = *(const float4*)&Ws[wg*3+2][k];
            acc0 = fmaf(a.x,w0.x, fmaf(a.y,w0.y, fmaf(a.z,w0.z, fmaf(a.w,w0.w, acc0))));
            acc1 = fmaf(a.x,w1.x, fmaf(a.y,w1.y, fmaf(a.z,w1.z, fmaf(a.w,w1.w, acc1))));
            acc2 = fmaf(a.x,w2.x, fmaf(a.y,w2.y, fmaf(a.z,w2.z, fmaf(a.w,w2.w, acc2))));
        }
        __syncthreads();
    }
    Gs[r][wg*3+0]=acc0; Gs[r][wg*3+1]=acc1; Gs[r][wg*3+2]=acc2;
    __syncthreads();
    if (tid < 128){
        int bl = tid >> 3, j = tid & 7;
        int b = b0 + bl;
        int h = hb*8 + j;
        const float* girow = gi + ((size_t)b*NS + i)*H3;
        float bhr = b_hh[h], bhz = b_hh[512+h], bhn = b_hh[1024+h];
        float g1r = Gs[bl][j]      + bhr;
        float g1z = Gs[bl][8+j]    + bhz;
        float g1n = Gs[bl][16+j]   + bhn;
        float g2r = Gs[16+bl][j]   + bhr;
        float g2z = Gs[16+bl][8+j] + bhz;
        float g2n = Gs[16+bl][16+j]+ bhn;
        float ir = girow[h], iz = girow[512+h], inn = girow[1024+h];
        float h1p = xbuf[((size_t)b*NS + (i-1))*NH + h];
        float h2p = xbuf[((size_t)b*NS + rowidx[bl])*NH + h];
        float r1 = sigmf(ir+g1r), z1 = sigmf(iz+g1z);
        float n1 = tanhf(inn + r1*g1n);
        float hid1 = (1.f-z1)*n1 + z1*h1p;
        float r2 = sigmf(ir+g2r), z2 = sigmf(iz+g2z);
        float n2 = tanhf(inn + r2*g2n);
        float hid2 = (1.f-z2)*n2 + z2*h2p;
        float a0 = alpha[((size_t)b*NS+i)*2+0], a1 = alpha[((size_t)b*NS+i)*2+1];
        xbuf[((size_t)b*NS + i)*NH + h] = a0*hid1 + a1*hid2;
    }
}

// out_time: wave per row
__global__ void k_time(const float* __restrict__ xbuf, const float* __restrict__ W_time,
                       const float* __restrict__ b_time, float* __restrict__ out){
    int gw = (int)((blockIdx.x*(size_t)blockDim.x + threadIdx.x) >> 6);
    int lane = threadIdx.x & 63;
    if (gw >= NB*NS) return;
    const float* x = xbuf + (size_t)gw*NH;
    float s = 0.f;
    for (int k=lane;k<NH;k+=64) s += x[k]*W_time[k];
    for (int off=32; off; off>>=1) s += __shfl_down(s, off);
    if (lane == 0) out[gw] = s + b_time[0];
}

extern "C" void kernel_launch(void* const* d_in, const int* in_sizes, int n_in,
                              void* d_out, int out_size, void* d_ws, size_t ws_size,
                              hipStream_t stream){
    const float* src    = (const float*)d_in[0];
    const int*   lens   = (const int*)d_in[1];
    const int*   seq    = (const int*)d_in[2];
    const float* X      = (const float*)d_in[3];
    const float* A      = (const float*)d_in[4];
    const float* W_attn = (const float*)d_in[5];
    const float* a_attn = (const float*)d_in[6];
    const float* W_ih   = (const float*)d_in[7];
    const float* W_hh   = (const float*)d_in[8];
    const float* b_ih   = (const float*)d_in[9];
    const float* b_hh   = (const float*)d_in[10];
    const float* h0     = (const float*)d_in[11];
    const float* W_poi  = (const float*)d_in[12];
    const float* b_poi  = (const float*)d_in[13];
    const float* W_time = (const float*)d_in[14];
    const float* b_time = (const float*)d_in[15];
    const float* W_cat  = (const float*)d_in[16];
    const float* b_cat  = (const float*)d_in[17];

    char* ws = (char*)d_ws;
    float*  gi    = (float*)(ws + 0);                    // 8192*1536*4 = 50331648
    float*  xbuf  = (float*)(ws + 50331648);             // 8192*512*4 = 16777216
    double* wh1   = (double*)(ws + 67108864);            // 65536
    double* wh2   = (double*)(ws + 67174400);            // 65536
    double* c1d   = (double*)(ws + 67239936);            // 1024
    double* c2d   = (double*)(ws + 67240960);            // 1024
    float*  alpha = (float*)(ws + 67241984);             // 65536
    int*    idx   = (int*)(ws + 67307520);               // 32768
    float*  gh0   = (float*)(ws + 67340288);             // 6144

    float* out_poi  = (float*)d_out;                       // 8192 x 8192
    float* out_time = (float*)d_out + (size_t)8192*8192;   // 8192
    float* out_cat  = out_time + 8192;                     // 8192 x 400

    // phase 1: attention precompute
    k_prep_c<<<1, 128, 0, stream>>>(W_attn, a_attn, c1d, c2d);
    k_wh<<<32, 256, 0, stream>>>(X, c1d, c2d, wh1, wh2);
    k_gh0<<<6, 256, 0, stream>>>(h0, W_hh, b_hh, gh0);
    k_attn<<<2048, 256, 0, stream>>>(seq, lens, A, wh1, wh2, alpha, idx);

    // phase 2: gi = src @ W_ih^T + b_ih   (8192 x 1536, K=512)
    k_gemm_nt<<<dim3(12, 64), 256, 0, stream>>>(src, W_ih, b_ih, gi, NB*NS, H3, NE, H3);

    // phase 3: scan
    k_step0<<<128, 256, 0, stream>>>(gi, gh0, h0, xbuf);
    for (int i=1;i<NS;i++)
        k_step<<<dim3(64, 4), 256, 0, stream>>>(gi, W_hh, b_hh, alpha, idx, xbuf, i);

    // phase 4: output projections
    k_gemm_nt<<<dim3(64, 64), 256, 0, stream>>>(xbuf, W_poi, b_poi, out_poi, NB*NS, NPOI_, NH, NPOI_);
    k_gemm_nt<<<dim3(4, 64), 256, 0, stream>>>(xbuf, W_cat, b_cat, out_cat, NB*NS, NCAT_, NH, NCAT_);
    k_time<<<2048, 256, 0, stream>>>(xbuf, W_time, b_time, out_time);
}

// Round 2
// 1063.879 us; speedup vs baseline: 3.1344x; 3.1344x over previous
//
#include <hip/hip_runtime.h>
#include <math.h>

typedef __attribute__((ext_vector_type(8))) short short8;
typedef __attribute__((ext_vector_type(4))) float f32x4;

#define NB 64
#define NS 128
#define NE 512
#define NH 512
#define NPOI_ 8192
#define NCAT_ 400
#define NF_ 128
#define H3 1536
#define NEGV -1000000000.0

__device__ inline float sigmf(float x){ return 1.0f/(1.0f + expf(-x)); }
__device__ inline unsigned short f2bf(float f){
    unsigned u = __float_as_uint(f);
    unsigned r = (u + 0x7fffu + ((u>>16)&1u)) >> 16;
    return (unsigned short)r;
}
__device__ inline float bf2f(unsigned short b){
    return __uint_as_float(((unsigned)b)<<16);
}

// ---------- f32 -> bf16 conversion (n multiple of 4) ----------
__global__ void k_cvt(const float* __restrict__ in, unsigned short* __restrict__ out, int n){
    int t = blockIdx.x*blockDim.x + threadIdx.x;
    int i = t*4;
    if (i < n){
        float4 v = *(const float4*)(in + i);
        ushort4 o;
        o.x = f2bf(v.x); o.y = f2bf(v.y); o.z = f2bf(v.z); o.w = f2bf(v.w);
        *(ushort4*)(out + i) = o;
    }
}

// ---------- phase 1: attention precompute (f64 for argmax stability) ----------
__global__ void k_prep_c(const float* __restrict__ W_attn, const float* __restrict__ a_attn,
                         double* __restrict__ c1d, double* __restrict__ c2d){
    int f = blockIdx.x*blockDim.x + threadIdx.x;
    if (f < NF_){
        double s1=0.0, s2=0.0;
        for (int k=0;k<NF_;k++){
            double w = (double)W_attn[f*NF_+k];
            s1 += w*(double)a_attn[k];
            s2 += w*(double)a_attn[NF_+k];
        }
        c1d[f]=s1; c2d[f]=s2;
    }
}

__global__ void k_wh(const float* __restrict__ X, const double* __restrict__ c1d,
                     const double* __restrict__ c2d, double* __restrict__ wh1, double* __restrict__ wh2){
    int p = blockIdx.x*blockDim.x + threadIdx.x;
    if (p < NPOI_){
        const float* x = X + (size_t)p*NF_;
        double s1=0.0,s2=0.0;
        for (int k=0;k<NF_;k++){ double xv=(double)x[k]; s1+=xv*c1d[k]; s2+=xv*c2d[k]; }
        wh1[p]=s1; wh2[p]=s2;
    }
}

__global__ void k_gh0(const float* __restrict__ h0, const float* __restrict__ W_hh,
                      const float* __restrict__ b_hh, float* __restrict__ gh0){
    int c = blockIdx.x*blockDim.x + threadIdx.x;
    if (c < H3){
        const float* w = W_hh + (size_t)c*NH;
        float s=0.f;
        for (int k=0;k<NH;k++) s += h0[k]*w[k];
        gh0[c] = s + b_hh[c];
    }
}

__device__ inline double shfl_down_d(double x, int off){
    long long v = __double_as_longlong(x);
    int lo = (int)(v & 0xffffffffLL), hi = (int)(((unsigned long long)v)>>32);
    lo = __shfl_down(lo, off); hi = __shfl_down(hi, off);
    return __longlong_as_double(((long long)hi<<32) | (unsigned long long)(unsigned int)lo);
}

__global__ void k_attn(const int* __restrict__ seq, const int* __restrict__ lens,
                       const float* __restrict__ A, const double* __restrict__ wh1,
                       const double* __restrict__ wh2, float* __restrict__ alpha,
                       int* __restrict__ idxout){
    int gw = (int)((blockIdx.x*(size_t)blockDim.x + threadIdx.x) >> 6);
    int lane = threadIdx.x & 63;
    if (gw >= NB*NS) return;
    int b = gw >> 7, j = gw & 127;
    int len = lens[b];
    int q = seq[b*NS + j];
    double wq = wh2[q];
    bool jvalid = (j < len);
    double mval = -1.0e300; int mk = 0;
    for (int k0=0;k0<NS;k0+=64){
        int k = k0 + lane;
        double val = NEGV;
        if (k < j && jvalid){
            int p = seq[b*NS + k];
            double e = wh1[p] + wq;
            e = (e > 0.0) ? e : 0.2*e;
            val = e * ((double)A[(size_t)p*NPOI_ + q] + 1.0);
        }
        if (val > mval){ mval = val; mk = k; }
    }
    for (int off=32; off; off>>=1){
        double ov = shfl_down_d(mval, off);
        int ok = __shfl_down(mk, off);
        if (ov > mval || (ov == mval && ok < mk)){ mval = ov; mk = ok; }
    }
    if (lane == 0){
        double v0 = mval;
        double v1;
        if (j == 0) v1 = 0.0;
        else if (!jvalid) v1 = NEGV;
        else {
            int p = seq[b*NS + j - 1];
            double e = wh1[p] + wq;
            e = (e > 0.0) ? e : 0.2*e;
            v1 = e * ((double)A[(size_t)p*NPOI_ + q] + 1.0);
        }
        double m = fmax(v0, v1);
        double e0 = exp(v0 - m), e1 = exp(v1 - m);
        double den = e0 + e1;
        alpha[(size_t)(b*NS+j)*2 + 0] = (float)(e0/den);
        alpha[(size_t)(b*NS+j)*2 + 1] = (float)(e1/den);
        idxout[b*NS + j] = mk;
    }
}

// ---------- bf16 MFMA NT GEMM: C[r,c] = sum_k A[r,k]*B[c,k] + bias[c] ----------
// M multiple of 128; N guarded. 128x128 tile, BK=64, 4 waves (2x2), 64x64/wave.
#define LDT 88
__global__ __launch_bounds__(256) void k_gemm_bf16(const unsigned short* __restrict__ A,
        const unsigned short* __restrict__ B, const float* __restrict__ bias,
        float* __restrict__ C, int M, int N, int K, int ldc){
    __shared__ unsigned short As[128][LDT];
    __shared__ unsigned short Bs[128][LDT];
    int row0 = blockIdx.y*128, col0 = blockIdx.x*128;
    int tid = threadIdx.x;
    int lane = tid & 63, w = tid >> 6;
    int wr = w >> 1, wc = w & 1;
    int lr = lane & 15, lk = lane >> 4;
    f32x4 acc[4][4] = {};
    for (int k0 = 0; k0 < K; k0 += 64){
        #pragma unroll
        for (int q = 0; q < 4; q++){
            int c = tid + 256*q;
            int r = c >> 3, ko = (c & 7)*8;
            *(short8*)&As[r][ko] = *(const short8*)(A + (size_t)(row0+r)*K + k0 + ko);
            int gc = col0 + r;
            short8 bv = {};
            if (gc < N) bv = *(const short8*)(B + (size_t)gc*K + k0 + ko);
            *(short8*)&Bs[r][ko] = bv;
        }
        __syncthreads();
        #pragma unroll
        for (int ks = 0; ks < 2; ks++){
            int kf = ks*32 + lk*8;
            short8 af[4], bf_[4];
            #pragma unroll
            for (int m=0;m<4;m++) af[m] = *(const short8*)&As[wr*64 + m*16 + lr][kf];
            #pragma unroll
            for (int n=0;n<4;n++) bf_[n] = *(const short8*)&Bs[wc*64 + n*16 + lr][kf];
            #pragma unroll
            for (int m=0;m<4;m++)
                #pragma unroll
                for (int n=0;n<4;n++)
                    acc[m][n] = __builtin_amdgcn_mfma_f32_16x16x32_bf16(af[m], bf_[n], acc[m][n], 0,0,0);
        }
        __syncthreads();
    }
    #pragma unroll
    for (int m=0;m<4;m++){
        #pragma unroll
        for (int n=0;n<4;n++){
            int col = col0 + wc*64 + n*16 + lr;
            if (col < N){
                float bb = bias[col];
                #pragma unroll
                for (int j=0;j<4;j++){
                    int row = row0 + wr*64 + m*16 + lk*4 + j;
                    C[(size_t)row*ldc + col] = acc[m][n][j] + bb;
                }
            }
        }
    }
}

// ---------- scan ----------
__global__ void k_step0(const float* __restrict__ gi, const float* __restrict__ gh0,
                        const float* __restrict__ h0, float* __restrict__ xf,
                        unsigned short* __restrict__ xb){
    int t = blockIdx.x*blockDim.x + threadIdx.x;
    if (t >= NB*NH) return;
    int b = t >> 9, h = t & 511;
    const float* g = gi + (size_t)b*NS*H3;
    float r = sigmf(g[h] + gh0[h]);
    float z = sigmf(g[512+h] + gh0[512+h]);
    float n = tanhf(g[1024+h] + r*gh0[1024+h]);
    float v = (1.f-z)*n + z*h0[h];
    size_t o = (size_t)b*NS*NH + h;
    xf[o] = v;
    xb[o] = f2bf(v);
}

// per-step MFMA kernel. grid (128 h-groups, 2 batch-halves), 256 threads.
// Block computes gh for 32 batches x {hid1,hid2} x 12 gate-cols (4 h), then gates.
__global__ __launch_bounds__(256) void k_step_mfma(const float* __restrict__ gi,
        const unsigned short* __restrict__ Whh, const float* __restrict__ bhh,
        const float* __restrict__ alpha, const int* __restrict__ idx,
        float* __restrict__ xf, unsigned short* __restrict__ xb, int i){
    __shared__ unsigned short Ws[16][520];
    __shared__ float ghs[64][20];
    __shared__ int rowidx[32];
    int hg = blockIdx.x, bh = blockIdx.y;
    int h0 = hg*4;
    int tid = threadIdx.x;
    // stage 12 W rows (cols ordered: 0-3 = r gates, 4-7 = z, 8-11 = n)
    for (int c = tid; c < 768; c += 256){
        int rr = c >> 6, ko = (c & 63)*8;
        int g = rr >> 2, j = rr & 3;
        *(short8*)&Ws[rr][ko] = *(const short8*)(Whh + (size_t)(g*512 + h0 + j)*NH + ko);
    }
    for (int c = tid; c < 4*520; c += 256) Ws[12 + c/520][c%520] = 0;
    if (tid < 32) rowidx[tid] = idx[(bh*32 + tid)*NS + i];
    __syncthreads();
    int lane = tid & 63, w = tid >> 6;
    int lr = lane & 15, lk = lane >> 4;
    int mrow = w*16 + lr;              // 0..63: rows 0-31 = hid1 path, 32-63 = hid2 path
    int b32 = mrow & 31, var = mrow >> 5;
    int b = bh*32 + b32;
    int srow = var ? rowidx[b32] : (i-1);
    const unsigned short* ap = xb + ((size_t)b*NS + srow)*NH + lk*8;
    f32x4 acc = {};
    #pragma unroll
    for (int ks = 0; ks < 16; ks++){
        short8 a = *(const short8*)(ap + ks*32);
        short8 bfr = *(const short8*)&Ws[lr][ks*32 + lk*8];
        acc = __builtin_amdgcn_mfma_f32_16x16x32_bf16(a, bfr, acc, 0,0,0);
    }
    #pragma unroll
    for (int j=0;j<4;j++) ghs[w*16 + lk*4 + j][lr] = acc[j];
    __syncthreads();
    if (tid < 128){
        int bb = tid & 31, hp = (tid >> 5) & 3;
        int bg = bh*32 + bb;
        int h = h0 + hp;
        float g1r = ghs[bb][hp],    g1z = ghs[bb][4+hp],    g1n = ghs[bb][8+hp];
        float g2r = ghs[32+bb][hp], g2z = ghs[32+bb][4+hp], g2n = ghs[32+bb][8+hp];
        float bhr = bhh[h], bhz = bhh[512+h], bhn = bhh[1024+h];
        const float* gir = gi + ((size_t)bg*NS + i)*H3;
        float ir = gir[h], iz = gir[512+h], inn = gir[1024+h];
        float h1p = xf[((size_t)bg*NS + i-1)*NH + h];
        float h2p = xf[((size_t)bg*NS + rowidx[bb])*NH + h];
        float r1 = sigmf(ir + g1r + bhr), z1 = sigmf(iz + g1z + bhz);
        float n1 = tanhf(inn + r1*(g1n + bhn));
        float hid1 = (1.f-z1)*n1 + z1*h1p;
        float r2 = sigmf(ir + g2r + bhr), z2 = sigmf(iz + g2z + bhz);
        float n2 = tanhf(inn + r2*(g2n + bhn));
        float hid2 = (1.f-z2)*n2 + z2*h2p;
        float a0 = alpha[((size_t)bg*NS+i)*2+0], a1 = alpha[((size_t)bg*NS+i)*2+1];
        float v = a0*hid1 + a1*hid2;
        size_t o = ((size_t)bg*NS + i)*NH + h;
        xf[o] = v;
        xb[o] = f2bf(v);
    }
}

// out_time: wave per row (reads f32 state)
__global__ void k_time(const float* __restrict__ xf, const float* __restrict__ W_time,
                       const float* __restrict__ b_time, float* __restrict__ out){
    int gw = (int)((blockIdx.x*(size_t)blockDim.x + threadIdx.x) >> 6);
    int lane = threadIdx.x & 63;
    if (gw >= NB*NS) return;
    const float* x = xf + (size_t)gw*NH;
    float s = 0.f;
    for (int k=lane;k<NH;k+=64) s += x[k]*W_time[k];
    for (int off=32; off; off>>=1) s += __shfl_down(s, off);
    if (lane == 0) out[gw] = s + b_time[0];
}

extern "C" void kernel_launch(void* const* d_in, const int* in_sizes, int n_in,
                              void* d_out, int out_size, void* d_ws, size_t ws_size,
                              hipStream_t stream){
    const float* src    = (const float*)d_in[0];
    const int*   lens   = (const int*)d_in[1];
    const int*   seq    = (const int*)d_in[2];
    const float* X      = (const float*)d_in[3];
    const float* A      = (const float*)d_in[4];
    const float* W_attn = (const float*)d_in[5];
    const float* a_attn = (const float*)d_in[6];
    const float* W_ih   = (const float*)d_in[7];
    const float* W_hh   = (const float*)d_in[8];
    const float* b_ih   = (const float*)d_in[9];
    const float* b_hh   = (const float*)d_in[10];
    const float* h0     = (const float*)d_in[11];
    const float* W_poi  = (const float*)d_in[12];
    const float* b_poi  = (const float*)d_in[13];
    const float* W_time = (const float*)d_in[14];
    const float* b_time = (const float*)d_in[15];
    const float* W_cat  = (const float*)d_in[16];
    const float* b_cat  = (const float*)d_in[17];

    // ws layout (~36 MB)
    char* ws = (char*)d_ws;
    float*          xf      = (float*)(ws + 0);               // 64*128*512*4 = 16777216
    unsigned short* xb      = (unsigned short*)(ws + 16777216); // 8388608
    unsigned short* Whh_bf  = (unsigned short*)(ws + 25165824); // 1572864
    unsigned short* Wpoi_bf = (unsigned short*)(ws + 26738688); // 8388608
    unsigned short* Wcat_bf = (unsigned short*)(ws + 35127296); // 409600
    double*         wh1     = (double*)(ws + 35536896);       // 65536
    double*         wh2     = (double*)(ws + 35602432);       // 65536
    double*         c1d     = (double*)(ws + 35667968);       // 1024
    double*         c2d     = (double*)(ws + 35668992);       // 1024
    float*          alpha   = (float*)(ws + 35670016);        // 65536
    int*            idx     = (int*)(ws + 35735552);          // 32768
    float*          gh0     = (float*)(ws + 35768320);        // 6144

    // scratch inside the out_poi region of d_out (dead before out_poi GEMM runs)
    char* ob = (char*)d_out;
    unsigned short* src_bf = (unsigned short*)(ob + 0);         // 8388608
    unsigned short* Wih_bf = (unsigned short*)(ob + 9437184);   // 1572864
    float*          gi     = (float*)(ob + 16777216);           // 50331648 (ends at 67.1 MB < 268 MB)

    float* out_poi  = (float*)d_out;                        // 8192 x 8192
    float* out_time = (float*)d_out + (size_t)8192*8192;    // 8192
    float* out_cat  = out_time + 8192;                      // 8192 x 400

    // conversions
    k_cvt<<<4096, 256, 0, stream>>>(src, src_bf, NB*NS*NE);
    k_cvt<<<768, 256, 0, stream>>>(W_ih, Wih_bf, H3*NE);
    k_cvt<<<768, 256, 0, stream>>>(W_hh, Whh_bf, H3*NH);
    k_cvt<<<4096, 256, 0, stream>>>(W_poi, Wpoi_bf, NPOI_*NH);
    k_cvt<<<200, 256, 0, stream>>>(W_cat, Wcat_bf, NCAT_*NH);

    // attention path (f64, exact argmax)
    k_prep_c<<<1, 128, 0, stream>>>(W_attn, a_attn, c1d, c2d);
    k_wh<<<32, 256, 0, stream>>>(X, c1d, c2d, wh1, wh2);
    k_gh0<<<6, 256, 0, stream>>>(h0, W_hh, b_hh, gh0);
    k_attn<<<2048, 256, 0, stream>>>(seq, lens, A, wh1, wh2, alpha, idx);

    // gi = src @ W_ih^T + b_ih  (8192 x 1536, K=512)
    k_gemm_bf16<<<dim3(12, 64), 256, 0, stream>>>(src_bf, Wih_bf, b_ih, gi, NB*NS, H3, NE, H3);

    // scan
    k_step0<<<128, 256, 0, stream>>>(gi, gh0, h0, xf, xb);
    for (int i=1;i<NS;i++)
        k_step_mfma<<<dim3(128, 2), 256, 0, stream>>>(gi, Whh_bf, b_hh, alpha, idx, xf, xb, i);

    // output projections
    k_gemm_bf16<<<dim3(64, 64), 256, 0, stream>>>(xb, Wpoi_bf, b_poi, out_poi, NB*NS, NPOI_, NH, NPOI_);
    k_gemm_bf16<<<dim3(4, 64), 256, 0, stream>>>(xb, Wcat_bf, b_cat, out_cat, NB*NS, NCAT_, NH, NCAT_);
    k_time<<<2048, 256, 0, stream>>>(xf, W_time, b_time, out_time);
}